// Round 1
// 1608.581 us; speedup vs baseline: 3.5694x; 3.5694x over previous
//
#include <hip/hip_runtime.h>

// Fused grouped conv: x(128,6,256,256) fp32, VALID 5x5, out(128,16,252,252).
// oc 0-5  = CH3 groups (3 in-ch each), oc 6-14 = CH4 groups (4 in-ch),
// oc 15   = CH6 (all 6 ch). Each input channel feeds exactly 10 outputs.
//
// Consumer tables (hardcoded from reference CH3/CH4/CH6):
// kind: 0 -> w3 (oc=g),  1 -> w4 (oc=6+g),  2 -> w6 (oc=15, pos=c)
namespace {
constexpr int CKIND[6][10] = {
  {0,0,0, 1,1,1,1,1,1, 2},
  {0,0,0, 1,1,1,1,1,1, 2},
  {0,0,0, 1,1,1,1,1,1, 2},
  {0,0,0, 1,1,1,1,1,1, 2},
  {0,0,0, 1,1,1,1,1,1, 2},
  {0,0,0, 1,1,1,1,1,1, 2},
};
constexpr int CG[6][10] = {
  {0,4,5, 0,3,4,5,6,8, 0},
  {0,1,5, 0,1,4,5,6,7, 0},
  {0,1,2, 0,1,2,5,7,8, 0},
  {1,2,3, 0,1,2,3,6,8, 0},
  {2,3,4, 1,2,3,4,6,7, 0},
  {3,4,5, 2,3,4,5,7,8, 0},
};
constexpr int CPOS[6][10] = {
  {0,0,0, 0,0,0,0,0,0, 0},
  {1,0,1, 1,0,1,1,1,0, 1},
  {2,1,0, 2,1,0,2,1,1, 2},
  {2,1,0, 3,2,1,1,2,2, 3},
  {2,1,1, 3,2,2,2,3,2, 4},
  {2,2,2, 3,3,3,3,3,3, 5},
};
} // namespace

#define TW 64
#define TH 16
#define IW 68   // TW+4
#define IH 20   // TH+4
#define LDS_CH (IH*IW)  // 1360 floats per channel

// launch_bounds(256, 2): 2 waves/EU min -> VGPR budget 256/wave.
// Previous (256, 4) capped the allocator at 128 and the backend clamped to
// 64 VGPRs, spilling the 64-reg accumulator array to scratch (rocprof showed
// 16.6 GB HBM traffic vs ~0.8 GB ideal, VALUBusy 8.5%). acc[16][4] + r[8]
// + addressing ~= 100-120 VGPRs, which must stay fully in registers.
__global__ __launch_bounds__(256, 2)
void conv_fused(const float* __restrict__ x,
                const float* __restrict__ w3, const float* __restrict__ b3,
                const float* __restrict__ w4, const float* __restrict__ b4,
                const float* __restrict__ w6, const float* __restrict__ b6,
                float* __restrict__ out)
{
  __shared__ __align__(16) float smem[6 * LDS_CH];
  const int tid = threadIdx.x;
  const int bx = blockIdx.x;       // 0..3   x-tiles
  const int by = blockIdx.y;       // 0..15  y-tiles
  const int b  = blockIdx.z;       // batch
  const int x0 = bx * TW;
  const int y0 = by * TH;

  // ---- stage 6 x 20 x 68 input tile into LDS (float4, zero-fill OOB) ----
  const float* xb = x + (size_t)b * 6 * 256 * 256;
  for (int i = tid; i < 6 * IH * 17; i += 256) {
    int row = i / 17;            // 0..119
    int v   = i - row * 17;      // 0..16 (float4 index within row)
    int c   = row / IH;
    int y   = row - c * IH;
    int gy  = y0 + y;
    int gx  = x0 + v * 4;
    float4 val = make_float4(0.f, 0.f, 0.f, 0.f);
    if (gy < 256 && gx < 256)
      val = *(const float4*)(xb + ((size_t)c * 256 + gy) * 256 + gx);
    *(float4*)(&smem[c * LDS_CH + y * IW + v * 4]) = val;
  }
  __syncthreads();

  const int tx = (tid & 15) * 4;   // output col within tile: 0,4,...,60
  const int ty = tid >> 4;         // output row within tile: 0..15

  // ---- accumulators: 16 oc x 4 px, init with bias ----
  float acc[16][4];
  #pragma unroll
  for (int oc = 0; oc < 16; ++oc) {
    float bv = (oc < 6) ? b3[oc] : (oc < 15 ? b4[oc - 6] : b6[0]);
    #pragma unroll
    for (int p = 0; p < 4; ++p) acc[oc][p] = bv;
  }

  // ---- main loop: fully unrolled, sparse pattern compile-time ----
  #pragma unroll
  for (int c = 0; c < 6; ++c) {
    #pragma unroll
    for (int ky = 0; ky < 5; ++ky) {
      const float* rp = &smem[c * LDS_CH + (ty + ky) * IW + tx];
      float4 ra = *(const float4*)rp;
      float4 rb = *(const float4*)(rp + 4);
      float r[8] = {ra.x, ra.y, ra.z, ra.w, rb.x, rb.y, rb.z, rb.w};
      #pragma unroll
      for (int kx = 0; kx < 5; ++kx) {
        const int tap = ky * 5 + kx;
        #pragma unroll
        for (int j = 0; j < 10; ++j) {
          const int kind = CKIND[c][j];
          const int g    = CG[c][j];
          const int pos  = CPOS[c][j];
          float wv;
          if (kind == 0)      wv = w3[(g * 3 + pos) * 25 + tap];
          else if (kind == 1) wv = w4[(g * 4 + pos) * 25 + tap];
          else                wv = w6[pos * 25 + tap];
          const int oc = (kind == 0) ? g : ((kind == 1) ? 6 + g : 15);
          #pragma unroll
          for (int p = 0; p < 4; ++p)
            acc[oc][p] = fmaf(r[kx + p], wv, acc[oc][p]);
        }
      }
    }
  }

  // ---- store: float4 per oc, guarded (252 % 4 == 0 so vec4 guard is exact) ----
  const int oy = y0 + ty;
  const int ox = x0 + tx;
  if (oy < 252 && ox < 252) {
    float* ob = out + (((size_t)b * 16) * 252 + oy) * 252 + ox;
    #pragma unroll
    for (int oc = 0; oc < 16; ++oc) {
      float4 v = make_float4(acc[oc][0], acc[oc][1], acc[oc][2], acc[oc][3]);
      *(float4*)(ob + (size_t)oc * 252 * 252) = v;
    }
  }
}

extern "C" void kernel_launch(void* const* d_in, const int* in_sizes, int n_in,
                              void* d_out, int out_size, void* d_ws, size_t ws_size,
                              hipStream_t stream) {
  const float* x  = (const float*)d_in[0];
  const float* w3 = (const float*)d_in[1];
  const float* b3 = (const float*)d_in[2];
  const float* w4 = (const float*)d_in[3];
  const float* b4 = (const float*)d_in[4];
  const float* w6 = (const float*)d_in[5];
  const float* b6 = (const float*)d_in[6];
  float* out = (float*)d_out;

  dim3 grid(4, 16, 128);   // x-tiles, y-tiles, batch
  dim3 block(256);
  hipLaunchKernelGGL(conv_fused, grid, block, 0, stream,
                     x, w3, b3, w4, b4, w6, b6, out);
}